// Round 4
// baseline (132.921 us; speedup 1.0000x reference)
//
#include <hip/hip_runtime.h>
#include <hip/hip_bf16.h>
#include <hip/hip_fp8.h>

typedef __attribute__((ext_vector_type(4))) int i32x4;
typedef __attribute__((ext_vector_type(8))) int i32x8;
typedef __attribute__((ext_vector_type(16))) float f32x16;

#define MARGIN 0.3f
#define BIGF 3.0e38f

__device__ __forceinline__ f32x16 mx_mfma(i32x8 a, i32x8 b, f32x16 c) {
    return __builtin_amdgcn_mfma_scale_f32_32x32x64_f8f6f4(
        a, b, c, 0 /*A fmt fp8*/, 0 /*B fmt fp8*/,
        0, 127 /*scale A = 2^0*/, 0, 127 /*scale B = 2^0*/);
}

// 32B fragment load (one cell slice for this lane): two dwordx4.
__device__ __forceinline__ i32x8 ld32(const unsigned char* p) {
    i32x4 lo = *(const i32x4*)p;
    i32x4 hi = *(const i32x4*)(p + 16);
    return __builtin_shufflevector(lo, hi, 0, 1, 2, 3, 4, 5, 6, 7);
}

// Wave-per-row convert: fp32 -> fp8 e4m3 (OCP) cast, fp32 row norm of the
// fp8-ROUNDED values (consistent with MFMA dots -> exact diagonal), init
// ap/an/cnt. NEW in R4: output is written in FRAGMENT-NATIVE tiled layout
// Xf[p][t][l][32B]: row = p*32 + (l&31), k = t*64 + (l>>5)*32 + byte.
// Cell (p,t) = 2 KB contiguous = exactly one wave's MFMA operand fragment
// (lane l's 32 B at l*32). Same bytes as before, just re-addressed ->
// numerics bit-identical.
__global__ __launch_bounds__(256) void convert_norm_kernel(
    const float* __restrict__ X, unsigned char* __restrict__ Xf,
    float* __restrict__ nrm, unsigned* __restrict__ ap,
    unsigned* __restrict__ an, unsigned* __restrict__ cnt, int K) {
    const int wave = threadIdx.x >> 6, lane = threadIdx.x & 63;
    const int row = blockIdx.x * 4 + wave;
    const float* xr = X + (size_t)row * K;
    const size_t pbase = ((size_t)(row >> 5)) << 16;  // p * 65536
    const int rsub = row & 31;
    float s = 0.0f;
    for (int c = lane * 8; c < K; c += 64 * 8) {
        float4 v0 = *(const float4*)(xr + c);
        float4 v1 = *(const float4*)(xr + c + 4);
        float f[8] = {v0.x, v0.y, v0.z, v0.w, v1.x, v1.y, v1.z, v1.w};
        union { unsigned char b[8]; uint2 u; } p;
#pragma unroll
        for (int i = 0; i < 8; i++) {
            __hip_fp8_e4m3 q(f[i]);       // OCP e4m3, RNE+saturate
            p.b[i] = q.__x;
            float d = (float)q;           // decoded value
            s += d * d;
        }
        // Fragment-native address: cell (row>>5, c>>6), lane-slot
        // rsub + 32*((c>>5)&1), byte c&31 (multiple of 8 -> aligned uint2).
        const int lslot = rsub + (((c >> 5) & 1) << 5);
        unsigned char* dst = Xf + pbase + ((size_t)(c >> 6) << 11)
                             + (lslot << 5) + (c & 31);
        *(uint2*)dst = p.u;
    }
    for (int off = 32; off > 0; off >>= 1) s += __shfl_xor(s, off, 64);
    if (lane == 0) {
        nrm[row] = s;
        ap[row] = 0u;           // dist_ap >= 0 always (self is a positive)
        an[row] = 0x7F800000u;  // +inf
        if (row == 0) *cnt = 0u;
    }
}

// FULL-SQUARE fp8-MX GEMM-reduce, BARRIER-FREE register dataflow.
// R0-R3 post-mortem: four different sync structures (single-buffer drain,
// 2-phase raw-barrier, 4-phase counted-vmcnt, double-XOR-swizzled) all
// cost the same per K-tile -> the stage->barrier->read->barrier lockstep
// itself is the invariant limiter, not conflicts or waitcnt placement.
// This version deletes the entire LDS staging path: operands are loaded
// straight from the fragment-native Xf layout (cell (p,t) = 2 KB = one
// wave fragment, lane l reads its 32 B at l*32 via two dwordx4, perfectly
// coalesced). Main loop = 8 global loads + 4 MFMA per k64 step, no LDS,
// no __syncthreads, no gl2lds -> the compiler software-pipelines plain
// loads (vmcnt-counted) and 4 blocks/CU give TLP. Pipe floors: MFMA
// 14.7 us, L2 traffic ~1 GB (L2-resident, ~29 us at aggregate ceiling,
// less with L1 hits on the 2x intra-block fragment reuse).
// Geometry unchanged: 128x128 tiles, 1024 blocks = 4.0/CU, 4 waves (2x2),
// wave tile 64x64 = 2x2 subtiles of 32x32x64 mfma_scale (unit scales
// 0x7F). Carried verbatim (R0-verified): C/D map col=lane&31,
// row=(reg&3)+8*(reg>>2)+4*(lane>>5), row-side hard-pos/neg reduction,
// monotone uint atomics, fused last-block loss.
__global__ __launch_bounds__(256, 4) void gemm_reduce_kernel(
    const unsigned char* __restrict__ Xf, const float* __restrict__ nrm,
    const int* __restrict__ Y, unsigned* __restrict__ ap,
    unsigned* __restrict__ an, unsigned* __restrict__ cnt,
    float* __restrict__ out, int N, int K) {
    __shared__ int sYr[128], sYc[128];
    __shared__ float sNr[128], sNc[128];
    __shared__ float redmax[4][64], redmin[4][64];
    __shared__ float lsum[4];
    __shared__ unsigned s_done;

    const int tid = threadIdx.x;
    const int wave = tid >> 6;
    const int lane = tid & 63;
    const int m = lane & 31;   // row within 32x32 subtile / col within subtile
    const int h = lane >> 5;   // k-half (inputs) / row-group (outputs)
    const int wr = wave >> 1;  // wave row (0..1): rows wr*64..+63
    const int wc = wave & 1;   // wave col (0..1): cols wc*64..+63

    const int NB = N >> 7;  // 32
    const int rowBase = (blockIdx.x >> 5) * 128;
    const int colBase = (blockIdx.x & (NB - 1)) * 128;

    if (tid < 128) {
        sYr[tid] = Y[rowBase + tid];
        sNr[tid] = nrm[rowBase + tid];
    } else {
        int t = tid - 128;
        sYc[t] = Y[colBase + t];
        sNc[t] = nrm[colBase + t];
    }
    __syncthreads();  // sY/sN visible to all waves (main loop has no syncs)

    f32x16 acc[2][2];
#pragma unroll
    for (int si = 0; si < 2; si++)
#pragma unroll
        for (int sj = 0; sj < 2; sj++)
#pragma unroll
            for (int rr = 0; rr < 16; rr++) acc[si][sj][rr] = 0.0f;

    // Fragment base pointers. Panel index p = global_row/32. Wave (wr,wc)
    // consumes A panels rowBase/32 + wr*2 + {0,1} and B panels
    // colBase/32 + wc*2 + {0,1}. Cell (p,t) lives at p*65536 + t*2048;
    // this lane's 32 B slice at + lane*32.
    const unsigned char* a0 =
        Xf + (((size_t)(rowBase >> 5) + wr * 2) << 16) + lane * 32;
    const unsigned char* a1 = a0 + 65536;
    const unsigned char* b0 =
        Xf + (((size_t)(colBase >> 5) + wc * 2) << 16) + lane * 32;
    const unsigned char* b1 = b0 + 65536;

    const int nt = K >> 6;  // 32 k64-steps
#pragma unroll 4
    for (int t = 0; t < nt; t++) {
        const size_t off = (size_t)t << 11;  // t * 2048
        i32x8 af0 = ld32(a0 + off);
        i32x8 af1 = ld32(a1 + off);
        i32x8 bf0 = ld32(b0 + off);
        i32x8 bf1 = ld32(b1 + off);
        acc[0][0] = mx_mfma(af0, bf0, acc[0][0]);
        acc[0][1] = mx_mfma(af0, bf1, acc[0][1]);
        acc[1][0] = mx_mfma(af1, bf0, acc[1][0]);
        acc[1][1] = mx_mfma(af1, bf1, acc[1][1]);
    }

    // Epilogue: ROW-side only (full G). C/D: col (within subtile) = m,
    // row64 (within wave's 64 rows) = si*32 + (reg&3) + 8*(reg>>2) + 4*h.
#pragma unroll
    for (int si = 0; si < 2; si++)
#pragma unroll
        for (int reg = 0; reg < 16; reg++) {
            const int row64 = si * 32 + (reg & 3) + 8 * (reg >> 2) + 4 * h;
            const int rIdx = wr * 64 + row64;  // row within block tile
            const int yr = sYr[rIdx];
            const float nr = sNr[rIdx];
            float dp = -1.0f, dn = BIGF;
#pragma unroll
            for (int sj = 0; sj < 2; sj++) {
                const int cIdx = wc * 64 + sj * 32 + m;
                float d2 = nr + sNc[cIdx] - 2.0f * acc[si][sj][reg];
                float d = sqrtf(fmaxf(d2, 0.0f));
                bool same = (yr == sYc[cIdx]);
                dp = fmaxf(dp, same ? d : -1.0f);
                dn = fminf(dn, same ? BIGF : d);
            }
            // Reduce over the 32 col-lanes (offsets 1..16 keep h fixed).
            for (int off = 1; off < 32; off <<= 1) {
                dp = fmaxf(dp, __shfl_xor(dp, off, 64));
                dn = fminf(dn, __shfl_xor(dn, off, 64));
            }
            if (m == 0) {  // lanes 0 (h=0) and 32 (h=1): disjoint row64 sets
                redmax[wave][row64] = dp;
                redmin[wave][row64] = dn;
            }
        }
    __syncthreads();

    // Combine the two wc waves of each wr half; one atomic pair per row.
    // Non-negative floats: uint cmp == float cmp; clamp max to 0 (true
    // dist_ap >= 0 via the diagonal self-pair).
    if (tid < 128) {
        const int wr2 = tid >> 6, r64 = tid & 63;
        float mx = fmaxf(redmax[wr2 * 2][r64], redmax[wr2 * 2 + 1][r64]);
        float mn = fminf(redmin[wr2 * 2][r64], redmin[wr2 * 2 + 1][r64]);
        atomicMax(&ap[rowBase + tid], __float_as_uint(fmaxf(mx, 0.0f)));
        atomicMin(&an[rowBase + tid], __float_as_uint(mn));
    }

    // Last block computes the loss (release fence before counter increment;
    // acquire fence + agent-scope atomic loads in the last block).
    __syncthreads();
    if (tid == 0) {
        __threadfence();
        s_done = atomicAdd(cnt, 1u);
    }
    __syncthreads();
    if (s_done == gridDim.x - 1) {
        __threadfence();
        float s = 0.0f;
        for (int i = tid; i < N; i += 256) {
            unsigned ua = __hip_atomic_load(&ap[i], __ATOMIC_RELAXED,
                                            __HIP_MEMORY_SCOPE_AGENT);
            unsigned ub = __hip_atomic_load(&an[i], __ATOMIC_RELAXED,
                                            __HIP_MEMORY_SCOPE_AGENT);
            s += fmaxf(__uint_as_float(ua) - __uint_as_float(ub) + MARGIN, 0.0f);
        }
        for (int off = 32; off > 0; off >>= 1) s += __shfl_xor(s, off, 64);
        if (lane == 0) lsum[wave] = s;
        __syncthreads();
        if (tid == 0)
            out[0] = (lsum[0] + lsum[1] + lsum[2] + lsum[3]) / (float)N;
    }
}

extern "C" void kernel_launch(void* const* d_in, const int* in_sizes, int n_in,
                              void* d_out, int out_size, void* d_ws, size_t ws_size,
                              hipStream_t stream) {
    const float* X = (const float*)d_in[0];
    const int* Y = (const int*)d_in[1];
    float* out = (float*)d_out;
    const int N = in_sizes[1];          // 4096
    const int K = in_sizes[0] / N;      // 2048

    char* ws = (char*)d_ws;
    unsigned char* Xf = (unsigned char*)ws;                         // N*K bytes
    float* nrm = (float*)(ws + (size_t)N * K);
    unsigned* ap = (unsigned*)((char*)nrm + (size_t)N * 4);
    unsigned* an = (unsigned*)((char*)ap + (size_t)N * 4);
    unsigned* cnt = (unsigned*)((char*)an + (size_t)N * 4);

    convert_norm_kernel<<<N / 4, 256, 0, stream>>>(X, Xf, nrm, ap, an, cnt, K);
    const int NB = N / 128;
    gemm_reduce_kernel<<<NB * NB, 256, 0, stream>>>(Xf, nrm, Y, ap, an, cnt,
                                                    out, N, K);
}

// Round 5
// 128.594 us; speedup vs baseline: 1.0337x; 1.0337x over previous
//
#include <hip/hip_runtime.h>
#include <hip/hip_bf16.h>
#include <hip/hip_fp8.h>

typedef __attribute__((ext_vector_type(4))) int i32x4;
typedef __attribute__((ext_vector_type(8))) int i32x8;
typedef __attribute__((ext_vector_type(16))) float f32x16;

#define MARGIN 0.3f
#define BIGF 3.0e38f

__device__ __forceinline__ f32x16 mx_mfma(i32x8 a, i32x8 b, f32x16 c) {
    return __builtin_amdgcn_mfma_scale_f32_32x32x64_f8f6f4(
        a, b, c, 0 /*A fmt fp8*/, 0 /*B fmt fp8*/,
        0, 127 /*scale A = 2^0*/, 0, 127 /*scale B = 2^0*/);
}

// 32B fragment load (one cell slice for this lane): two dwordx4.
__device__ __forceinline__ i32x8 ld32(const unsigned char* p) {
    i32x4 lo = *(const i32x4*)p;
    i32x4 hi = *(const i32x4*)(p + 16);
    return __builtin_shufflevector(lo, hi, 0, 1, 2, 3, 4, 5, 6, 7);
}

// Wave-per-row convert: fp32 -> fp8 e4m3 (OCP) cast, fp32 row norm of the
// fp8-ROUNDED values (consistent with MFMA dots -> exact diagonal), init
// ap/an/cnt. Output in FRAGMENT-NATIVE tiled layout Xf[p][t][l][32B]:
// row = p*32 + (l&31), k = t*64 + (l>>5)*32 + byte. Cell (p,t) = 2 KB
// contiguous = one wave MFMA operand fragment. (R4-verified; UNCHANGED.)
__global__ __launch_bounds__(256) void convert_norm_kernel(
    const float* __restrict__ X, unsigned char* __restrict__ Xf,
    float* __restrict__ nrm, unsigned* __restrict__ ap,
    unsigned* __restrict__ an, unsigned* __restrict__ cnt, int K) {
    const int wave = threadIdx.x >> 6, lane = threadIdx.x & 63;
    const int row = blockIdx.x * 4 + wave;
    const float* xr = X + (size_t)row * K;
    const size_t pbase = ((size_t)(row >> 5)) << 16;  // p * 65536
    const int rsub = row & 31;
    float s = 0.0f;
    for (int c = lane * 8; c < K; c += 64 * 8) {
        float4 v0 = *(const float4*)(xr + c);
        float4 v1 = *(const float4*)(xr + c + 4);
        float f[8] = {v0.x, v0.y, v0.z, v0.w, v1.x, v1.y, v1.z, v1.w};
        union { unsigned char b[8]; uint2 u; } p;
#pragma unroll
        for (int i = 0; i < 8; i++) {
            __hip_fp8_e4m3 q(f[i]);       // OCP e4m3, RNE+saturate
            p.b[i] = q.__x;
            float d = (float)q;           // decoded value
            s += d * d;
        }
        // Fragment-native address: cell (row>>5, c>>6), lane-slot
        // rsub + 32*((c>>5)&1), byte c&31 (multiple of 8 -> aligned uint2).
        const int lslot = rsub + (((c >> 5) & 1) << 5);
        unsigned char* dst = Xf + pbase + ((size_t)(c >> 6) << 11)
                             + (lslot << 5) + (c & 31);
        *(uint2*)dst = p.u;
    }
    for (int off = 32; off > 0; off >>= 1) s += __shfl_xor(s, off, 64);
    if (lane == 0) {
        nrm[row] = s;
        ap[row] = 0u;           // dist_ap >= 0 always (self is a positive)
        an[row] = 0x7F800000u;  // +inf
        if (row == 0) *cnt = 0u;
    }
}

// FULL-SQUARE fp8-MX GEMM-reduce, register dataflow v2.
// R0-R4 post-mortem: five structures all ~65 us; R4 (no LDS, no barriers)
// tied R0 -> limiter is the cache->reg path: (a) VGPR_Count=56 showed the
// compiler kept ~1 k-step in flight (L2/LLC latency exposed every step),
// (b) 64x64 wave tiles move 2 KB/MFMA through the ~64 B/cy L1 return
// path (128 KB/CU-step = 2048 cy vs 1100 cy MFMA).
// v2: (1) wave tile 64x128 = 2x4 subtiles -> 6 cell-loads per 8 MFMA =
// 1.5 KB/MFMA, and B-cells are shared by all 4 waves (L1 hits);
// (2) explicit 2-deep register double-buffer (named A0/B0/A1/B1, static
// indexing) -> ~96 operand VGPRs of lookahead hide L2 latency under the
// 8-MFMA cluster. Block = 256x128, grid 16x32 = 512 = exactly 2/CU
// (8 waves/CU). No LDS in the main loop at all.
// Epilogue simplification: each wave owns 64 COMPLETE rows (all 128 block
// cols) -> per-row hard-pos/neg reduces in-wave (4 sj in-register + shfl
// over 32 lanes), atomics issued directly from m==0 lanes; redmax/redmin
// LDS arrays and their barrier are gone.
// Numerics bit-identical to R4: same fragment bytes, same per-acc K-order
// (t = 0..31 ascending), max/min merge order-independent.
// Carried verbatim (R0-verified): C/D map col=lane&31,
// row=(reg&3)+8*(reg>>2)+4*(lane>>5), monotone uint atomics (non-negative
// floats: uint cmp == float cmp), fused last-block loss.
__global__ __launch_bounds__(256, 2) void gemm_reduce_kernel(
    const unsigned char* __restrict__ Xf, const float* __restrict__ nrm,
    const int* __restrict__ Y, unsigned* __restrict__ ap,
    unsigned* __restrict__ an, unsigned* __restrict__ cnt,
    float* __restrict__ out, int N, int K) {
    __shared__ int sYr[256], sYc[128];
    __shared__ float sNr[256], sNc[128];
    __shared__ float lsum[4];
    __shared__ unsigned s_done;

    const int tid = threadIdx.x;
    const int wave = tid >> 6;
    const int lane = tid & 63;
    const int m = lane & 31;   // col within 32x32 subtile (outputs)
    const int h = lane >> 5;   // row-group (outputs)

    const int rowBase = (blockIdx.x >> 5) << 8;  // 16 row-blocks of 256
    const int colBase = (blockIdx.x & 31) << 7;  // 32 col-blocks of 128

    if (tid < 256) {
        sYr[tid] = Y[rowBase + tid];
        sNr[tid] = nrm[rowBase + tid];
    }
    if (tid < 128) {
        sYc[tid] = Y[colBase + tid];
        sNc[tid] = nrm[colBase + tid];
    }

    f32x16 acc[2][4];
#pragma unroll
    for (int si = 0; si < 2; si++)
#pragma unroll
        for (int sj = 0; sj < 4; sj++)
#pragma unroll
            for (int rr = 0; rr < 16; rr++) acc[si][sj][rr] = 0.0f;

    // Fragment base pointers. Panel p = global_row/32; cell (p,t) at
    // p*65536 + t*2048; this lane's 32 B at + lane*32. Wave owns A panels
    // rowBase/32 + wave*2 + {0,1}; block shares B panels colBase/32+{0..3}.
    const unsigned char* pa[2];
    const unsigned char* pb[4];
#pragma unroll
    for (int si = 0; si < 2; si++)
        pa[si] = Xf + (((size_t)(rowBase >> 5) + wave * 2 + si) << 16) + lane * 32;
#pragma unroll
    for (int sj = 0; sj < 4; sj++)
        pb[sj] = Xf + (((size_t)(colBase >> 5) + sj) << 16) + lane * 32;

    i32x8 A0[2], B0[4], A1[2], B1[4];

#define LD(Ab, Bb, t)                                                   \
    do {                                                                \
        const size_t _o = (size_t)(t) << 11;                            \
        _Pragma("unroll") for (int _i = 0; _i < 2; _i++)                \
            Ab[_i] = ld32(pa[_i] + _o);                                 \
        _Pragma("unroll") for (int _j = 0; _j < 4; _j++)                \
            Bb[_j] = ld32(pb[_j] + _o);                                 \
    } while (0)

#define MM(Ab, Bb)                                                      \
    do {                                                                \
        _Pragma("unroll") for (int _i = 0; _i < 2; _i++)                \
            _Pragma("unroll") for (int _j = 0; _j < 4; _j++)            \
                acc[_i][_j] = mx_mfma(Ab[_i], Bb[_j], acc[_i][_j]);     \
    } while (0)

    const int nt = K >> 6;  // 32 k64-steps
    LD(A0, B0, 0);
    int t = 0;
    for (; t + 2 < nt; t += 2) {
        LD(A1, B1, t + 1);
        MM(A0, B0);
        LD(A0, B0, t + 2);
        MM(A1, B1);
    }
    LD(A1, B1, t + 1);  // t == nt-2
    MM(A0, B0);
    MM(A1, B1);

#undef LD
#undef MM

    __syncthreads();  // sY/sN visible (no earlier barrier needed)

    // Epilogue: each wave owns rows rowBase + wave*64 + row64 across the
    // block's full 128 cols. C/D: col = sj*32 + m, row64 = si*32 +
    // (reg&3) + 8*(reg>>2) + 4*h.
#pragma unroll
    for (int si = 0; si < 2; si++)
#pragma unroll
        for (int reg = 0; reg < 16; reg++) {
            const int row64 = si * 32 + (reg & 3) + 8 * (reg >> 2) + 4 * h;
            const int rIdx = wave * 64 + row64;  // row within block tile
            const int yr = sYr[rIdx];
            const float nr = sNr[rIdx];
            float dp = -1.0f, dn = BIGF;
#pragma unroll
            for (int sj = 0; sj < 4; sj++) {
                const int cIdx = sj * 32 + m;
                float d2 = nr + sNc[cIdx] - 2.0f * acc[si][sj][reg];
                float d = sqrtf(fmaxf(d2, 0.0f));
                bool same = (yr == sYc[cIdx]);
                dp = fmaxf(dp, same ? d : -1.0f);
                dn = fminf(dn, same ? BIGF : d);
            }
            // Reduce over the 32 col-lanes (offsets 1..16 keep h fixed).
            for (int off = 1; off < 32; off <<= 1) {
                dp = fmaxf(dp, __shfl_xor(dp, off, 64));
                dn = fminf(dn, __shfl_xor(dn, off, 64));
            }
            if (m == 0) {  // lanes 0 (h=0) and 32 (h=1): disjoint row64 sets
                atomicMax(&ap[rowBase + rIdx], __float_as_uint(fmaxf(dp, 0.0f)));
                atomicMin(&an[rowBase + rIdx], __float_as_uint(dn));
            }
        }

    // Last block computes the loss (release fence before counter increment;
    // acquire fence + agent-scope atomic loads in the last block).
    __syncthreads();
    if (tid == 0) {
        __threadfence();
        s_done = atomicAdd(cnt, 1u);
    }
    __syncthreads();
    if (s_done == gridDim.x - 1) {
        __threadfence();
        float s = 0.0f;
        for (int i = tid; i < N; i += 256) {
            unsigned ua = __hip_atomic_load(&ap[i], __ATOMIC_RELAXED,
                                            __HIP_MEMORY_SCOPE_AGENT);
            unsigned ub = __hip_atomic_load(&an[i], __ATOMIC_RELAXED,
                                            __HIP_MEMORY_SCOPE_AGENT);
            s += fmaxf(__uint_as_float(ua) - __uint_as_float(ub) + MARGIN, 0.0f);
        }
        for (int off = 32; off > 0; off >>= 1) s += __shfl_xor(s, off, 64);
        if (lane == 0) lsum[wave] = s;
        __syncthreads();
        if (tid == 0)
            out[0] = (lsum[0] + lsum[1] + lsum[2] + lsum[3]) / (float)N;
    }
}

extern "C" void kernel_launch(void* const* d_in, const int* in_sizes, int n_in,
                              void* d_out, int out_size, void* d_ws, size_t ws_size,
                              hipStream_t stream) {
    const float* X = (const float*)d_in[0];
    const int* Y = (const int*)d_in[1];
    float* out = (float*)d_out;
    const int N = in_sizes[1];          // 4096
    const int K = in_sizes[0] / N;      // 2048

    char* ws = (char*)d_ws;
    unsigned char* Xf = (unsigned char*)ws;                         // N*K bytes
    float* nrm = (float*)(ws + (size_t)N * K);
    unsigned* ap = (unsigned*)((char*)nrm + (size_t)N * 4);
    unsigned* an = (unsigned*)((char*)ap + (size_t)N * 4);
    unsigned* cnt = (unsigned*)((char*)an + (size_t)N * 4);

    convert_norm_kernel<<<N / 4, 256, 0, stream>>>(X, Xf, nrm, ap, an, cnt, K);
    const int NBr = N / 256, NBc = N / 128;
    gemm_reduce_kernel<<<NBr * NBc, 256, 0, stream>>>(Xf, nrm, Y, ap, an, cnt,
                                                      out, N, K);
}